// Round 3
// baseline (130.553 us; speedup 1.0000x reference)
//
#include <hip/hip_runtime.h>

namespace {

constexpr int K     = 6;
constexpr int KK    = 36;   // K*K
constexpr int DF    = 8;    // D_FEAT
constexpr int DLAT  = 16;
constexpr int NS    = 5;
constexpr int B     = 131072;
constexpr int M     = NS * B;           // 655360 rows of [K,K]
constexpr float EPS = 1e-20f;

// One thread per (sample, batch) pair m in [0, M).
// b = m % B, noise row = m. Does: log_alpha = latent[b]@W_sink + b_sink,
// add gumbel(noise[m]), 5 Sinkhorn iterations (row then col logsumexp),
// exp, then ordered[m] = sink^T @ seq[b].
__global__ __launch_bounds__(256) void sink_kernel(
    const float* __restrict__ latent,
    const float* __restrict__ seq,
    const float* __restrict__ noise,
    const float* __restrict__ W_sink,
    const float* __restrict__ b_sink,
    float* __restrict__ out)
{
    const int m = blockIdx.x * 256 + threadIdx.x;
    if (m >= M) return;
    const int b = m & (B - 1);

    // latent[b][0..15] via 4x float4
    float lat[DLAT];
    const float4* lat4 = reinterpret_cast<const float4*>(latent + (size_t)b * DLAT);
    #pragma unroll
    for (int k = 0; k < 4; ++k) {
        float4 v = lat4[k];
        lat[k*4+0] = v.x; lat[k*4+1] = v.y; lat[k*4+2] = v.z; lat[k*4+3] = v.w;
    }

    // log_alpha = latent @ W_sink + b_sink; W/b indices are compile-time
    // constants -> uniform addresses -> compiler emits scalar loads (K$).
    float la[KK];
    #pragma unroll
    for (int i = 0; i < KK; ++i) la[i] = b_sink[i];
    #pragma unroll
    for (int k = 0; k < DLAT; ++k) {
        const float lv = lat[k];
        #pragma unroll
        for (int i = 0; i < KK; ++i)
            la[i] = fmaf(lv, W_sink[k*KK + i], la[i]);
    }

    // Gumbel: la += -log(EPS - log(u + EPS))   (NOISE_FACTOR=1, TEMP=1)
    {
        const float4* n4 = reinterpret_cast<const float4*>(noise + (size_t)m * KK);
        float u[KK];
        #pragma unroll
        for (int q = 0; q < 9; ++q) {
            float4 v = n4[q];
            u[q*4+0] = v.x; u[q*4+1] = v.y; u[q*4+2] = v.z; u[q*4+3] = v.w;
        }
        #pragma unroll
        for (int i = 0; i < KK; ++i)
            la[i] += -__logf(EPS - __logf(u[i] + EPS));
    }

    // 5 Sinkhorn iterations: subtract row-lse (axis=2), then col-lse (axis=1)
    #pragma unroll
    for (int it = 0; it < 5; ++it) {
        #pragma unroll
        for (int i = 0; i < K; ++i) {            // rows: lse over j
            float mx = la[i*K+0];
            #pragma unroll
            for (int j = 1; j < K; ++j) mx = fmaxf(mx, la[i*K+j]);
            float s = 0.f;
            #pragma unroll
            for (int j = 0; j < K; ++j) s += __expf(la[i*K+j] - mx);
            const float lse = mx + __logf(s);
            #pragma unroll
            for (int j = 0; j < K; ++j) la[i*K+j] -= lse;
        }
        #pragma unroll
        for (int j = 0; j < K; ++j) {            // cols: lse over i
            float mx = la[0*K+j];
            #pragma unroll
            for (int i = 1; i < K; ++i) mx = fmaxf(mx, la[i*K+j]);
            float s = 0.f;
            #pragma unroll
            for (int i = 0; i < K; ++i) s += __expf(la[i*K+j] - mx);
            const float lse = mx + __logf(s);
            #pragma unroll
            for (int i = 0; i < K; ++i) la[i*K+j] -= lse;
        }
    }

    // sink = exp(la); ordered[m,i,d] = sum_j sink[j,i] * seq[b,j,d]
    float p[KK];
    #pragma unroll
    for (int i = 0; i < KK; ++i) p[i] = __expf(la[i]);

    float o[K*DF];
    #pragma unroll
    for (int i = 0; i < K*DF; ++i) o[i] = 0.f;

    const float4* s4 = reinterpret_cast<const float4*>(seq + (size_t)b * (K*DF));
    #pragma unroll
    for (int j = 0; j < K; ++j) {
        float4 a0 = s4[j*2 + 0];
        float4 a1 = s4[j*2 + 1];
        float srow[DF] = {a0.x, a0.y, a0.z, a0.w, a1.x, a1.y, a1.z, a1.w};
        #pragma unroll
        for (int i = 0; i < K; ++i) {
            const float pv = p[j*K + i];
            #pragma unroll
            for (int d = 0; d < DF; ++d)
                o[i*DF + d] = fmaf(pv, srow[d], o[i*DF + d]);
        }
    }

    float4* o4 = reinterpret_cast<float4*>(out + (size_t)m * (K*DF));
    #pragma unroll
    for (int q = 0; q < 12; ++q) {
        float4 v;
        v.x = o[q*4+0]; v.y = o[q*4+1]; v.z = o[q*4+2]; v.w = o[q*4+3];
        o4[q] = v;
    }
}

// stopping = softmax(latent @ W_mask + b_mask, axis=1), one thread per b
__global__ __launch_bounds__(256) void mask_kernel(
    const float* __restrict__ latent,
    const float* __restrict__ W_mask,
    const float* __restrict__ b_mask,
    float* __restrict__ outp)
{
    const int b = blockIdx.x * 256 + threadIdx.x;
    if (b >= B) return;

    float lat[DLAT];
    const float4* lat4 = reinterpret_cast<const float4*>(latent + (size_t)b * DLAT);
    #pragma unroll
    for (int k = 0; k < 4; ++k) {
        float4 v = lat4[k];
        lat[k*4+0] = v.x; lat[k*4+1] = v.y; lat[k*4+2] = v.z; lat[k*4+3] = v.w;
    }

    float v[K];
    #pragma unroll
    for (int i = 0; i < K; ++i) v[i] = b_mask[i];
    #pragma unroll
    for (int k = 0; k < DLAT; ++k) {
        const float lv = lat[k];
        #pragma unroll
        for (int i = 0; i < K; ++i)
            v[i] = fmaf(lv, W_mask[k*K + i], v[i]);
    }

    float mx = v[0];
    #pragma unroll
    for (int i = 1; i < K; ++i) mx = fmaxf(mx, v[i]);
    float s = 0.f;
    #pragma unroll
    for (int i = 0; i < K; ++i) { v[i] = __expf(v[i] - mx); s += v[i]; }
    const float inv = 1.f / s;
    #pragma unroll
    for (int i = 0; i < K; ++i) v[i] *= inv;

    // 6 floats per row; 8B-aligned float2 stores
    float2* o2 = reinterpret_cast<float2*>(outp + (size_t)b * K);
    o2[0] = make_float2(v[0], v[1]);
    o2[1] = make_float2(v[2], v[3]);
    o2[2] = make_float2(v[4], v[5]);
}

} // namespace

extern "C" void kernel_launch(void* const* d_in, const int* in_sizes, int n_in,
                              void* d_out, int out_size, void* d_ws, size_t ws_size,
                              hipStream_t stream) {
    const float* latent = (const float*)d_in[0];
    const float* seq    = (const float*)d_in[1];
    const float* noise  = (const float*)d_in[2];
    const float* W_sink = (const float*)d_in[3];
    const float* b_sink = (const float*)d_in[4];
    const float* W_mask = (const float*)d_in[5];
    const float* b_mask = (const float*)d_in[6];
    float* out = (float*)d_out;

    sink_kernel<<<M / 256, 256, 0, stream>>>(latent, seq, noise, W_sink, b_sink, out);
    mask_kernel<<<B / 256, 256, 0, stream>>>(latent, W_mask, b_mask,
                                             out + (size_t)M * K * DF);
}

// Round 5
// 76.796 us; speedup vs baseline: 1.7000x; 1.7000x over previous
//
#include <hip/hip_runtime.h>

namespace {

constexpr int K     = 6;
constexpr int KK    = 36;   // K*K
constexpr int DF    = 8;    // D_FEAT
constexpr int DLAT  = 16;
constexpr int NS    = 5;
constexpr int B     = 131072;
constexpr int M     = NS * B;           // 655360 (sample, batch) pairs
constexpr float EPS = 1e-20f;

// One thread per (sample, batch) pair, BATCH-MAJOR: thread m -> b = m/5,
// s = m%5, so the 5 samples of one b sit in adjacent lanes (latent/seq
// fetched once, L1-broadcast). Sinkhorn runs in EXP domain: P = exp(la+g),
// then 5x (row-div, col-div) — mathematically identical to the reference's
// log-domain logsumexp normalization, and values are bounded well inside
// f32 range (max exp ~ e^51, min ratio ~ e^-60), so no stabilization needed.
__global__ __launch_bounds__(256) void sink_kernel(
    const float* __restrict__ latent,
    const float* __restrict__ seq,
    const float* __restrict__ noise,
    const float* __restrict__ W_sink,
    const float* __restrict__ b_sink,
    float* __restrict__ out)
{
    const int m = blockIdx.x * 256 + threadIdx.x;
    const int b = (int)((unsigned)m / 5u);        // mulhi magic, cheap
    const int s = m - b * 5;
    const size_t row = (size_t)s * B + b;         // noise / out row index

    // latent[b][0..15] via 4x float4 (5 adjacent lanes share b -> L1 hit)
    float lat[DLAT];
    const float4* lat4 = reinterpret_cast<const float4*>(latent + (size_t)b * DLAT);
    #pragma unroll
    for (int k = 0; k < 4; ++k) {
        float4 v = lat4[k];
        lat[k*4+0] = v.x; lat[k*4+1] = v.y; lat[k*4+2] = v.z; lat[k*4+3] = v.w;
    }

    // log_alpha = latent @ W_sink + b_sink; W/b wave-uniform -> scalar loads
    float la[KK];
    #pragma unroll
    for (int i = 0; i < KK; ++i) la[i] = b_sink[i];
    #pragma unroll
    for (int k = 0; k < DLAT; ++k) {
        const float lv = lat[k];
        #pragma unroll
        for (int i = 0; i < KK; ++i)
            la[i] = fmaf(lv, W_sink[k*KK + i], la[i]);
    }

    // P = exp(la + gumbel), gumbel = -log(EPS - log(u + EPS))
    float p[KK];
    {
        const float4* n4 = reinterpret_cast<const float4*>(noise + row * KK);
        float u[KK];
        #pragma unroll
        for (int q = 0; q < 9; ++q) {
            float4 v = n4[q];
            u[q*4+0] = v.x; u[q*4+1] = v.y; u[q*4+2] = v.z; u[q*4+3] = v.w;
        }
        #pragma unroll
        for (int i = 0; i < KK; ++i)
            p[i] = __expf(la[i] - __logf(EPS - __logf(u[i] + EPS)));
    }

    // 5 Sinkhorn iterations in exp domain: row-normalize then col-normalize
    #pragma unroll
    for (int it = 0; it < 5; ++it) {
        #pragma unroll
        for (int i = 0; i < K; ++i) {            // rows (axis=2)
            const float sum = ((p[i*K+0] + p[i*K+1]) + (p[i*K+2] + p[i*K+3]))
                            + (p[i*K+4] + p[i*K+5]);
            const float r = __builtin_amdgcn_rcpf(sum);
            #pragma unroll
            for (int j = 0; j < K; ++j) p[i*K+j] *= r;
        }
        #pragma unroll
        for (int j = 0; j < K; ++j) {            // cols (axis=1)
            const float sum = ((p[0*K+j] + p[1*K+j]) + (p[2*K+j] + p[3*K+j]))
                            + (p[4*K+j] + p[5*K+j]);
            const float r = __builtin_amdgcn_rcpf(sum);
            #pragma unroll
            for (int i = 0; i < K; ++i) p[i*K+j] *= r;
        }
    }

    // ordered[row,i,d] = sum_j P[j,i] * seq[b,j,d]   (P already exp'ed)
    float o[K*DF];
    #pragma unroll
    for (int i = 0; i < K*DF; ++i) o[i] = 0.f;

    const float4* s4 = reinterpret_cast<const float4*>(seq + (size_t)b * (K*DF));
    #pragma unroll
    for (int j = 0; j < K; ++j) {
        float4 a0 = s4[j*2 + 0];
        float4 a1 = s4[j*2 + 1];
        float srow[DF] = {a0.x, a0.y, a0.z, a0.w, a1.x, a1.y, a1.z, a1.w};
        #pragma unroll
        for (int i = 0; i < K; ++i) {
            const float pv = p[j*K + i];
            #pragma unroll
            for (int d = 0; d < DF; ++d)
                o[i*DF + d] = fmaf(pv, srow[d], o[i*DF + d]);
        }
    }

    float4* o4 = reinterpret_cast<float4*>(out + row * (K*DF));
    #pragma unroll
    for (int q = 0; q < 12; ++q) {
        float4 v;
        v.x = o[q*4+0]; v.y = o[q*4+1]; v.z = o[q*4+2]; v.w = o[q*4+3];
        o4[q] = v;
    }
}

// stopping = softmax(latent @ W_mask + b_mask, axis=1), one thread per b
__global__ __launch_bounds__(256) void mask_kernel(
    const float* __restrict__ latent,
    const float* __restrict__ W_mask,
    const float* __restrict__ b_mask,
    float* __restrict__ outp)
{
    const int b = blockIdx.x * 256 + threadIdx.x;
    if (b >= B) return;

    float lat[DLAT];
    const float4* lat4 = reinterpret_cast<const float4*>(latent + (size_t)b * DLAT);
    #pragma unroll
    for (int k = 0; k < 4; ++k) {
        float4 v = lat4[k];
        lat[k*4+0] = v.x; lat[k*4+1] = v.y; lat[k*4+2] = v.z; lat[k*4+3] = v.w;
    }

    float v[K];
    #pragma unroll
    for (int i = 0; i < K; ++i) v[i] = b_mask[i];
    #pragma unroll
    for (int k = 0; k < DLAT; ++k) {
        const float lv = lat[k];
        #pragma unroll
        for (int i = 0; i < K; ++i)
            v[i] = fmaf(lv, W_mask[k*K + i], v[i]);
    }

    float mx = v[0];
    #pragma unroll
    for (int i = 1; i < K; ++i) mx = fmaxf(mx, v[i]);
    float sum = 0.f;
    #pragma unroll
    for (int i = 0; i < K; ++i) { v[i] = __expf(v[i] - mx); sum += v[i]; }
    const float inv = 1.f / sum;
    #pragma unroll
    for (int i = 0; i < K; ++i) v[i] *= inv;

    float2* o2 = reinterpret_cast<float2*>(outp + (size_t)b * K);
    o2[0] = make_float2(v[0], v[1]);
    o2[1] = make_float2(v[2], v[3]);
    o2[2] = make_float2(v[4], v[5]);
}

} // namespace

extern "C" void kernel_launch(void* const* d_in, const int* in_sizes, int n_in,
                              void* d_out, int out_size, void* d_ws, size_t ws_size,
                              hipStream_t stream) {
    const float* latent = (const float*)d_in[0];
    const float* seq    = (const float*)d_in[1];
    const float* noise  = (const float*)d_in[2];
    const float* W_sink = (const float*)d_in[3];
    const float* b_sink = (const float*)d_in[4];
    const float* W_mask = (const float*)d_in[5];
    const float* b_mask = (const float*)d_in[6];
    float* out = (float*)d_out;

    sink_kernel<<<M / 256, 256, 0, stream>>>(latent, seq, noise, W_sink, b_sink, out);
    mask_kernel<<<B / 256, 256, 0, stream>>>(latent, W_mask, b_mask,
                                             out + (size_t)M * K * DF);
}